// Round 1
// baseline (477.735 us; speedup 1.0000x reference)
//
#include <hip/hip_runtime.h>
#include <math.h>

// Pass 1: last-write-wins winner election. out (zeroed) viewed as u32;
// atomicMax with (p+1) leaves the highest (= last in pair order) pair index
// in each touched slot. Untouched slots stay 0 (== 0.0f).
__global__ void k_scatter_max(const int* __restrict__ src, const int* __restrict__ dst,
                              unsigned int* __restrict__ out, int P, long long N) {
    int p = blockIdx.x * blockDim.x + threadIdx.x;
    if (p >= P) return;
    long long slot = (long long)src[p] * N + (long long)dst[p];
    atomicMax(&out[slot], (unsigned int)(p + 1));
}

// Pass 2: compute dots[p]; read winner id from out (read-only here -> race
// free); stage value + winner flag in workspace.
__global__ void k_dots(const float4* __restrict__ ea, const int4* __restrict__ paths,
                       const float4* __restrict__ ev, const int* __restrict__ src,
                       const int* __restrict__ dst, const unsigned int* __restrict__ out,
                       float* __restrict__ wdots, unsigned int* __restrict__ wflag,
                       int P, long long N) {
    __shared__ float4 sev[32];            // edge_vector: 8 x 16 fp32 = 32 float4
    int t = threadIdx.x;
    if (t < 32) sev[t] = ev[t];
    __syncthreads();
    int p = blockIdx.x * blockDim.x + t;
    if (p >= P) return;

    int4 i0 = paths[(size_t)p * 2 + 0];
    int4 i1 = paths[(size_t)p * 2 + 1];
    int idxs[8] = {i0.x, i0.y, i0.z, i0.w, i1.x, i1.y, i1.z, i1.w};

    float acc = 0.0f;
#pragma unroll
    for (int l = 0; l < 8; ++l) {
        int idx = idxs[l];
        if (idx >= 0) {                   // mask: -1 entries contribute 0
            const float4* row = ea + (size_t)idx * 4;
            float4 a0 = row[0], a1 = row[1], a2 = row[2], a3 = row[3];
            float4 v0 = sev[l * 4 + 0], v1 = sev[l * 4 + 1];
            float4 v2 = sev[l * 4 + 2], v3 = sev[l * 4 + 3];
            acc += a0.x * v0.x + a0.y * v0.y + a0.z * v0.z + a0.w * v0.w;
            acc += a1.x * v1.x + a1.y * v1.y + a1.z * v1.z + a1.w * v1.w;
            acc += a2.x * v2.x + a2.y * v2.y + a2.z * v2.z + a2.w * v2.w;
            acc += a3.x * v3.x + a3.y * v3.y + a3.z * v3.z + a3.w * v3.w;
        }
    }
    acc *= 0.125f;                        // mean over full L=8 (matches torch/jax)

    long long slot = (long long)src[p] * N + (long long)dst[p];
    wdots[p] = acc;
    wflag[p] = (out[slot] == (unsigned int)(p + 1)) ? 1u : 0u;
}

// Pass 3: winners overwrite their slot with the float value.
__global__ void k_write(const int* __restrict__ src, const int* __restrict__ dst,
                        const float* __restrict__ wdots, const unsigned int* __restrict__ wflag,
                        float* __restrict__ out, int P, long long N) {
    int p = blockIdx.x * blockDim.x + threadIdx.x;
    if (p >= P) return;
    if (wflag[p]) {
        long long slot = (long long)src[p] * N + (long long)dst[p];
        out[slot] = wdots[p];
    }
}

extern "C" void kernel_launch(void* const* d_in, const int* in_sizes, int n_in,
                              void* d_out, int out_size, void* d_ws, size_t ws_size,
                              hipStream_t stream) {
    // inputs: 0=num_nodes(int,1) 1=edge_attr(f32,E*16) 2=src(int,P) 3=dst(int,P)
    //         4=paths(int,P*8) 5=edge_vector(f32,8*16)
    const float* edge_attr = (const float*)d_in[1];
    const int*   src       = (const int*)d_in[2];
    const int*   dst       = (const int*)d_in[3];
    const int*   paths     = (const int*)d_in[4];
    const float* ev        = (const float*)d_in[5];

    int P = in_sizes[2];
    long long N = (long long)llround(sqrt((double)out_size));   // 8192

    float*        out   = (float*)d_out;
    float*        wdots = (float*)d_ws;                          // P floats
    unsigned int* wflag = (unsigned int*)((char*)d_ws + (size_t)P * sizeof(float));

    hipMemsetAsync(d_out, 0, (size_t)out_size * sizeof(float), stream);

    const int B = 256;
    const int G = (P + B - 1) / B;
    k_scatter_max<<<G, B, 0, stream>>>(src, dst, (unsigned int*)out, P, N);
    k_dots<<<G, B, 0, stream>>>((const float4*)edge_attr, (const int4*)paths,
                                (const float4*)ev, src, dst, (const unsigned int*)out,
                                wdots, wflag, P, N);
    k_write<<<G, B, 0, stream>>>(src, dst, wdots, wflag, out, P, N);
}